// Round 1
// baseline (117.662 us; speedup 1.0000x reference)
//
#include <hip/hip_runtime.h>
#include <stdint.h>

#define BB   32
#define CC1  256
#define HH   56
#define WW   56
#define OHH  28
#define OWW  28
#define CC2  512
#define EPSV 1e-5f

static __device__ __forceinline__ int popc64(uint64_t v) {
    return __builtin_popcountll(v);
}

// Pack sign(x) bits: xbits[b][h][w][k] bit c = (x[b][64k+c][h][w] >= 0)
__global__ __launch_bounds__(256) void k_binx(const float* __restrict__ x,
                                              uint64_t* __restrict__ xbits) {
    int gid = blockIdx.x * 256 + threadIdx.x;         // 401408 threads
    const int NP = BB * HH * WW;                      // 100352 pixels
    int pix = gid % NP;
    int cg  = gid / NP;                               // 0..3
    int w = pix % WW;
    int h = (pix / WW) % HH;
    int b = pix / (HH * WW);
    const float* xp = x + ((size_t)(b * CC1 + cg * 64)) * (HH * WW) + h * WW + w;
    uint64_t bits = 0;
    #pragma unroll 8
    for (int c = 0; c < 64; ++c) {
        float v = xp[(size_t)c * (HH * WW)];
        bits |= (uint64_t)(v >= 0.0f) << c;
    }
    xbits[(size_t)pix * 4 + cg] = bits;
}

// Pack sign(w3): w3b[oc][tap][k] bit c = (w3[oc][64k+c][tap] >= 0)
__global__ __launch_bounds__(256) void k_packw3(const float* __restrict__ w3,
                                                uint64_t* __restrict__ w3b) {
    int id = blockIdx.x * 256 + threadIdx.x;          // 9216 threads
    int k   = id % 4;
    int tap = (id / 4) % 9;
    int oc  = id / 36;
    const float* wp = w3 + (size_t)oc * 2304 + (size_t)(k * 64) * 9 + tap;
    uint64_t bits = 0;
    #pragma unroll 8
    for (int c = 0; c < 64; ++c) {
        bits |= (uint64_t)(wp[c * 9] >= 0.0f) << c;
    }
    w3b[(size_t)(oc * 9 + tap) * 4 + k] = bits;
}

// Pack sign(w1): w1b[oc][k]
__global__ __launch_bounds__(256) void k_packw1(const float* __restrict__ w1,
                                                uint64_t* __restrict__ w1b) {
    int id = blockIdx.x * 256 + threadIdx.x;          // 2048 threads
    int k  = id % 4;
    int oc = id / 4;
    const float* wp = w1 + (size_t)oc * 256 + k * 64;
    uint64_t bits = 0;
    #pragma unroll 8
    for (int c = 0; c < 64; ++c) {
        bits |= (uint64_t)(wp[c] >= 0.0f) << c;
    }
    w1b[(size_t)oc * 4 + k] = bits;
}

// 3x3 stride-2 binary conv + BN + inline avgpool(x) -> h
__global__ __launch_bounds__(256) void k_conv3(const float* __restrict__ x,
                                               const uint64_t* __restrict__ xbits,
                                               const uint64_t* __restrict__ w3b,
                                               const float* __restrict__ g3,
                                               const float* __restrict__ b3,
                                               const float* __restrict__ m3,
                                               const float* __restrict__ v3,
                                               float* __restrict__ hbuf) {
    int loc = blockIdx.x * 256 + threadIdx.x;         // 25088 locations
    int ow = loc % OWW;
    int oh = (loc / OWW) % OHH;
    int b  = loc / (OHH * OWW);
    int ocg = blockIdx.y;                              // 0..7, 32 oc each

    uint64_t xw[9][4];
    bool valid[9];
    int nvalid = 0;
    #pragma unroll
    for (int t = 0; t < 9; ++t) {
        int kh = t / 3, kw = t % 3;
        int ih = 2 * oh - 1 + kh;                      // max 55, only -1 invalid
        int iw = 2 * ow - 1 + kw;
        bool v = (ih >= 0) && (iw >= 0);
        valid[t] = v;
        nvalid += v ? 1 : 0;
        int cih = v ? ih : 0;
        int ciw = v ? iw : 0;
        const uint64_t* p = xbits + ((size_t)((b * HH + cih) * WW + ciw)) * 4;
        #pragma unroll
        for (int k = 0; k < 4; ++k) xw[t][k] = p[k];
    }
    int base = nvalid * 256;

    for (int o = 0; o < 32; ++o) {
        int oc = ocg * 32 + o;
        const uint64_t* wb = w3b + (size_t)oc * 36;
        int tot = 0;
        #pragma unroll
        for (int t = 0; t < 9; ++t) {
            int pt = 0;
            #pragma unroll
            for (int k = 0; k < 4; ++k)
                pt += popc64(xw[t][k] ^ wb[t * 4 + k]);
            tot += valid[t] ? pt : 0;
        }
        float y   = (float)(base - 2 * tot);
        float inv = g3[oc] / sqrtf(v3[oc] + EPSV);
        float bnv = y * inv + (b3[oc] - m3[oc] * inv);
        const float* px = x + ((size_t)(b * CC1 + oc)) * (HH * WW) + (2 * oh) * WW + 2 * ow;
        float2 r0 = *(const float2*)(px);
        float2 r1 = *(const float2*)(px + WW);
        float pool = 0.25f * (r0.x + r0.y + r1.x + r1.y);
        hbuf[((size_t)(b * CC1 + oc)) * (OHH * OWW) + oh * OWW + ow] = bnv + pool;
    }
}

// Pack sign(h) bits: hbits[b][p][k]
__global__ __launch_bounds__(256) void k_binh(const float* __restrict__ hbuf,
                                              uint64_t* __restrict__ hbits) {
    int gid = blockIdx.x * 256 + threadIdx.x;         // 100352 threads
    const int NP = BB * OHH * OWW;                    // 25088
    int pix = gid % NP;
    int cg  = gid / NP;
    int p = pix % (OHH * OWW);
    int b = pix / (OHH * OWW);
    const float* hp = hbuf + ((size_t)(b * CC1 + cg * 64)) * (OHH * OWW) + p;
    uint64_t bits = 0;
    #pragma unroll 8
    for (int c = 0; c < 64; ++c) {
        bits |= (uint64_t)(hp[(size_t)c * (OHH * OWW)] >= 0.0f) << c;
    }
    hbits[(size_t)pix * 4 + cg] = bits;
}

// 1x1 binary conv (256->512) + BN + concat(h,h) shortcut -> out
__global__ __launch_bounds__(256) void k_conv1(const uint64_t* __restrict__ hbits,
                                               const uint64_t* __restrict__ w1b,
                                               const float* __restrict__ hbuf,
                                               const float* __restrict__ g1,
                                               const float* __restrict__ b1,
                                               const float* __restrict__ m1,
                                               const float* __restrict__ v1,
                                               float* __restrict__ out) {
    int loc = blockIdx.x * 256 + threadIdx.x;         // 25088
    int p = loc % (OHH * OWW);
    int b = loc / (OHH * OWW);
    int ocg = blockIdx.y;                              // 0..15, 32 oc each

    uint64_t hw[4];
    const uint64_t* hp = hbits + (size_t)loc * 4;
    #pragma unroll
    for (int k = 0; k < 4; ++k) hw[k] = hp[k];

    for (int o = 0; o < 32; ++o) {
        int oc = ocg * 32 + o;
        const uint64_t* wb = w1b + (size_t)oc * 4;
        int pop = 0;
        #pragma unroll
        for (int k = 0; k < 4; ++k)
            pop += popc64(hw[k] ^ wb[k]);
        float z   = (float)(256 - 2 * pop);
        float inv = g1[oc] / sqrtf(v1[oc] + EPSV);
        float bnv = z * inv + (b1[oc] - m1[oc] * inv);
        float hc = hbuf[((size_t)(b * CC1 + (oc & 255))) * (OHH * OWW) + p];
        out[((size_t)(b * CC2 + oc)) * (OHH * OWW) + p] = bnv + hc;
    }
}

extern "C" void kernel_launch(void* const* d_in, const int* in_sizes, int n_in,
                              void* d_out, int out_size, void* d_ws, size_t ws_size,
                              hipStream_t stream) {
    const float* x  = (const float*)d_in[0];
    const float* w3 = (const float*)d_in[1];
    const float* g3 = (const float*)d_in[2];
    const float* b3 = (const float*)d_in[3];
    const float* m3 = (const float*)d_in[4];
    const float* v3 = (const float*)d_in[5];
    const float* w1 = (const float*)d_in[6];
    const float* g1 = (const float*)d_in[7];
    const float* b1 = (const float*)d_in[8];
    const float* m1 = (const float*)d_in[9];
    const float* v1 = (const float*)d_in[10];
    float* out = (float*)d_out;

    uint8_t* ws = (uint8_t*)d_ws;
    uint64_t* xbits = (uint64_t*)(ws);                 // 3,211,264 B
    uint64_t* hbits = (uint64_t*)(ws + 3211264);       //   802,816 B
    uint64_t* w3b   = (uint64_t*)(ws + 4014080);       //    73,728 B
    uint64_t* w1b   = (uint64_t*)(ws + 4087808);       //    16,384 B
    float*    hbuf  = (float*)  (ws + 4104192);        // 25,690,112 B (total ~29.8 MB)

    k_binx  <<<dim3(401408 / 256), 256, 0, stream>>>(x, xbits);
    k_packw3<<<dim3(9216 / 256),   256, 0, stream>>>(w3, w3b);
    k_packw1<<<dim3(2048 / 256),   256, 0, stream>>>(w1, w1b);
    k_conv3 <<<dim3(98, 8),  256, 0, stream>>>(x, xbits, w3b, g3, b3, m3, v3, hbuf);
    k_binh  <<<dim3(100352 / 256), 256, 0, stream>>>(hbuf, hbits);
    k_conv1 <<<dim3(98, 16), 256, 0, stream>>>(hbits, w1b, hbuf, g1, b1, m1, v1, out);
}

// Round 2
// 97.177 us; speedup vs baseline: 1.2108x; 1.2108x over previous
//
#include <hip/hip_runtime.h>
#include <stdint.h>

#define BB   32
#define CC1  256
#define HH   56
#define WW   56
#define PH   57          // padded (top/left zero row+col)
#define OHH  28
#define OWW  28
#define NPIX (OHH*OWW)   // 784
#define CC2  512
#define EPSV 1e-5f

static __device__ __forceinline__ int popc64(uint64_t v) {
    return __builtin_popcountll(v);
}

// ---------- zero the padded bit buffer ----------
__global__ __launch_bounds__(256) void k_zero(uint64_t* __restrict__ p, int n) {
    int i = blockIdx.x * 256 + threadIdx.x;
    if (i < n) p[i] = 0ull;
}

// ---------- pack sign(x) into padded layout xbp[b][h+1][w+1][k] ----------
__global__ __launch_bounds__(256) void k_binx(const float* __restrict__ x,
                                              uint64_t* __restrict__ xbp) {
    int gid = blockIdx.x * 256 + threadIdx.x;         // 401408
    const int NP = BB * HH * WW;
    int pix = gid % NP;
    int cg  = gid / NP;                               // 0..3
    int w = pix % WW;
    int h = (pix / WW) % HH;
    int b = pix / (HH * WW);
    const float* xp = x + ((size_t)(b * CC1 + cg * 64)) * (HH * WW) + h * WW + w;
    uint64_t bits = 0;
    #pragma unroll 8
    for (int c = 0; c < 64; ++c) {
        bits |= (uint64_t)(xp[(size_t)c * (HH * WW)] >= 0.0f) << c;
    }
    xbp[((size_t)((b * PH + h + 1) * PH) + w + 1) * 4 + cg] = bits;
}

// ---------- pack sign(w3) into layout w3t[tap][oc][k] ----------
__global__ __launch_bounds__(256) void k_packw3(const float* __restrict__ w3,
                                                uint64_t* __restrict__ w3t) {
    int id = blockIdx.x * 256 + threadIdx.x;          // 9216
    int k   = id % 4;
    int tap = (id / 4) % 9;
    int oc  = id / 36;
    const float* wp = w3 + (size_t)oc * 2304 + (size_t)(k * 64) * 9 + tap;
    uint64_t bits = 0;
    #pragma unroll 8
    for (int c = 0; c < 64; ++c) {
        bits |= (uint64_t)(wp[c * 9] >= 0.0f) << c;
    }
    w3t[((size_t)tap * CC1 + oc) * 4 + k] = bits;
}

// ---------- pack sign(w1) + fold BN constants ----------
__global__ __launch_bounds__(256) void k_packw1_bn(const float* __restrict__ w1,
                                                   uint64_t* __restrict__ w1b,
                                                   const float* __restrict__ g3,
                                                   const float* __restrict__ b3,
                                                   const float* __restrict__ m3,
                                                   const float* __restrict__ v3,
                                                   const float* __restrict__ g1,
                                                   const float* __restrict__ b1,
                                                   const float* __restrict__ m1,
                                                   const float* __restrict__ v1,
                                                   float* __restrict__ sc3,
                                                   float* __restrict__ bi3,
                                                   float* __restrict__ sc1,
                                                   float* __restrict__ bi1) {
    int id = blockIdx.x * 256 + threadIdx.x;          // 2048
    int k  = id % 4;
    int oc = id / 4;
    const float* wp = w1 + (size_t)oc * 256 + k * 64;
    uint64_t bits = 0;
    #pragma unroll 8
    for (int c = 0; c < 64; ++c) {
        bits |= (uint64_t)(wp[c] >= 0.0f) << c;
    }
    w1b[(size_t)oc * 4 + k] = bits;
    if (k == 0) {
        float s1 = g1[oc] / sqrtf(v1[oc] + EPSV);
        sc1[oc] = s1;
        bi1[oc] = b1[oc] - m1[oc] * s1;
        if (oc < CC1) {
            float s3 = g3[oc] / sqrtf(v3[oc] + EPSV);
            sc3[oc] = s3;
            bi3[oc] = b3[oc] - m3[oc] * s3;
        }
    }
}

// ---------- per-oc padding corrections for conv3 ----------
__global__ __launch_bounds__(256) void k_corr(const uint64_t* __restrict__ w3t,
                                              int* __restrict__ ctop,
                                              int* __restrict__ cleft,
                                              int* __restrict__ ccorn) {
    int oc = blockIdx.x * 256 + threadIdx.x;          // 256
    if (oc >= CC1) return;
    int pt[9];
    #pragma unroll
    for (int t = 0; t < 9; ++t) {
        const uint64_t* p = w3t + ((size_t)t * CC1 + oc) * 4;
        pt[t] = popc64(p[0]) + popc64(p[1]) + popc64(p[2]) + popc64(p[3]);
    }
    ctop[oc]  = (256 - 2 * pt[0]) + (256 - 2 * pt[1]) + (256 - 2 * pt[2]);
    cleft[oc] = (256 - 2 * pt[0]) + (256 - 2 * pt[3]) + (256 - 2 * pt[6]);
    ccorn[oc] = (256 - 2 * pt[0]);
}

// ---------- 3x3 stride-2 binary conv + BN + avgpool shortcut ----------
__global__ __launch_bounds__(256, 4) void k_conv3(const float* __restrict__ x,
                                                  const uint64_t* __restrict__ xbp,
                                                  const uint64_t* __restrict__ w3t,
                                                  const float* __restrict__ sc3,
                                                  const float* __restrict__ bi3,
                                                  const int* __restrict__ ctop,
                                                  const int* __restrict__ cleft,
                                                  const int* __restrict__ ccorn,
                                                  float* __restrict__ hbuf) {
    int loc = blockIdx.x * 256 + threadIdx.x;         // 25088
    int ow = loc % OWW;
    int oh = (loc / OWW) % OHH;
    int b  = loc / NPIX;
    int ocg = blockIdx.y;                             // 0..31, 8 oc each

    int tot[8] = {0, 0, 0, 0, 0, 0, 0, 0};
    for (int kh = 0; kh < 3; ++kh) {
        // padded coords: row = 2*oh + kh, col base = 2*ow (taps kw=0..2 contiguous)
        const uint64_t* rp = xbp + ((size_t)((b * PH + 2 * oh + kh) * PH) + 2 * ow) * 4;
        uint64_t t0[4], t1[4], t2[4];
        #pragma unroll
        for (int k = 0; k < 4; ++k) { t0[k] = rp[k]; t1[k] = rp[4 + k]; t2[k] = rp[8 + k]; }
        const uint64_t* wrow = w3t + ((size_t)(kh * 3) * CC1 + ocg * 8) * 4;
        #pragma unroll
        for (int o = 0; o < 8; ++o) {
            const uint64_t* w0 = wrow + (size_t)o * 4;
            const uint64_t* w1p = w0 + (size_t)CC1 * 4;
            const uint64_t* w2p = w0 + (size_t)CC1 * 8;
            int s = tot[o];
            #pragma unroll
            for (int k = 0; k < 4; ++k) s += popc64(t0[k] ^ w0[k]);
            #pragma unroll
            for (int k = 0; k < 4; ++k) s += popc64(t1[k] ^ w1p[k]);
            #pragma unroll
            for (int k = 0; k < 4; ++k) s += popc64(t2[k] ^ w2p[k]);
            tot[o] = s;
        }
    }

    bool top  = (oh == 0);
    bool left = (ow == 0);
    #pragma unroll
    for (int o = 0; o < 8; ++o) {
        int oc = ocg * 8 + o;
        int corr = (top ? ctop[oc] : 0) + (left ? cleft[oc] : 0)
                 - ((top && left) ? ccorn[oc] : 0);
        float y = (float)(2304 - 2 * tot[o] - corr);
        const float* px = x + ((size_t)(b * CC1 + oc)) * (HH * WW) + (2 * oh) * WW + 2 * ow;
        float2 r0 = *(const float2*)(px);
        float2 r1 = *(const float2*)(px + WW);
        float pool = 0.25f * (r0.x + r0.y + r1.x + r1.y);
        hbuf[((size_t)(b * CC1 + oc)) * NPIX + oh * OWW + ow] = y * sc3[oc] + bi3[oc] + pool;
    }
}

// ---------- pack sign(h) ----------
__global__ __launch_bounds__(256) void k_binh(const float* __restrict__ hbuf,
                                              uint64_t* __restrict__ hbits) {
    int gid = blockIdx.x * 256 + threadIdx.x;         // 100352
    const int NP = BB * NPIX;
    int pix = gid % NP;
    int cg  = gid / NP;
    int p = pix % NPIX;
    int b = pix / NPIX;
    const float* hp = hbuf + ((size_t)(b * CC1 + cg * 64)) * NPIX + p;
    uint64_t bits = 0;
    #pragma unroll 8
    for (int c = 0; c < 64; ++c) {
        bits |= (uint64_t)(hp[(size_t)c * NPIX] >= 0.0f) << c;
    }
    hbits[(size_t)pix * 4 + cg] = bits;
}

// ---------- 1x1 binary conv + BN + concat(h,h) shortcut ----------
__global__ __launch_bounds__(256, 4) void k_conv1(const uint64_t* __restrict__ hbits,
                                                  const uint64_t* __restrict__ w1b,
                                                  const float* __restrict__ hbuf,
                                                  const float* __restrict__ sc1,
                                                  const float* __restrict__ bi1,
                                                  float* __restrict__ out) {
    int loc = blockIdx.x * 256 + threadIdx.x;         // 25088
    int p = loc % NPIX;
    int b = loc / NPIX;
    int ocg = blockIdx.y;                             // 0..31, 8 channel-pairs

    uint64_t hw[4];
    const uint64_t* hp = hbits + (size_t)loc * 4;
    #pragma unroll
    for (int k = 0; k < 4; ++k) hw[k] = hp[k];

    #pragma unroll
    for (int o = 0; o < 8; ++o) {
        int oc  = ocg * 8 + o;          // 0..255
        int oc2 = oc + CC1;             // 256..511
        const uint64_t* wa = w1b + (size_t)oc  * 4;
        const uint64_t* wb = w1b + (size_t)oc2 * 4;
        int pa = 0, pb = 0;
        #pragma unroll
        for (int k = 0; k < 4; ++k) pa += popc64(hw[k] ^ wa[k]);
        #pragma unroll
        for (int k = 0; k < 4; ++k) pb += popc64(hw[k] ^ wb[k]);
        float hc = hbuf[((size_t)(b * CC1 + oc)) * NPIX + p];
        float za = (float)(256 - 2 * pa) * sc1[oc]  + bi1[oc]  + hc;
        float zb = (float)(256 - 2 * pb) * sc1[oc2] + bi1[oc2] + hc;
        out[((size_t)(b * CC2 + oc))  * NPIX + p] = za;
        out[((size_t)(b * CC2 + oc2)) * NPIX + p] = zb;
    }
}

extern "C" void kernel_launch(void* const* d_in, const int* in_sizes, int n_in,
                              void* d_out, int out_size, void* d_ws, size_t ws_size,
                              hipStream_t stream) {
    const float* x  = (const float*)d_in[0];
    const float* w3 = (const float*)d_in[1];
    const float* g3 = (const float*)d_in[2];
    const float* b3 = (const float*)d_in[3];
    const float* m3 = (const float*)d_in[4];
    const float* v3 = (const float*)d_in[5];
    const float* w1 = (const float*)d_in[6];
    const float* g1 = (const float*)d_in[7];
    const float* b1 = (const float*)d_in[8];
    const float* m1 = (const float*)d_in[9];
    const float* v1 = (const float*)d_in[10];
    float* out = (float*)d_out;

    uint8_t* ws = (uint8_t*)d_ws;
    size_t off = 0;
    uint64_t* xbp   = (uint64_t*)(ws + off); off += (size_t)BB * PH * PH * 4 * 8;   // 3,326,976
    uint64_t* hbits = (uint64_t*)(ws + off); off += (size_t)BB * NPIX * 4 * 8;      //   802,816
    uint64_t* w3t   = (uint64_t*)(ws + off); off += (size_t)9 * CC1 * 4 * 8;        //    73,728
    uint64_t* w1b   = (uint64_t*)(ws + off); off += (size_t)CC2 * 4 * 8;            //    16,384
    float* sc3 = (float*)(ws + off); off += CC1 * 4;
    float* bi3 = (float*)(ws + off); off += CC1 * 4;
    float* sc1 = (float*)(ws + off); off += CC2 * 4;
    float* bi1 = (float*)(ws + off); off += CC2 * 4;
    int* ctop  = (int*)(ws + off); off += CC1 * 4;
    int* cleft = (int*)(ws + off); off += CC1 * 4;
    int* ccorn = (int*)(ws + off); off += CC1 * 4;
    float* hbuf = (float*)(ws + off);                                               // 25,690,112

    const int nxbp = BB * PH * PH * 4;                // 415,872 u64
    k_zero  <<<dim3((nxbp + 255) / 256), 256, 0, stream>>>(xbp, nxbp);
    k_binx  <<<dim3(401408 / 256), 256, 0, stream>>>(x, xbp);
    k_packw3<<<dim3(9216 / 256),   256, 0, stream>>>(w3, w3t);
    k_packw1_bn<<<dim3(2048 / 256), 256, 0, stream>>>(w1, w1b, g3, b3, m3, v3,
                                                      g1, b1, m1, v1, sc3, bi3, sc1, bi1);
    k_corr  <<<dim3(1), 256, 0, stream>>>(w3t, ctop, cleft, ccorn);
    k_conv3 <<<dim3(98, 32), 256, 0, stream>>>(x, xbp, w3t, sc3, bi3, ctop, cleft, ccorn, hbuf);
    k_binh  <<<dim3(100352 / 256), 256, 0, stream>>>(hbuf, hbits);
    k_conv1 <<<dim3(98, 32), 256, 0, stream>>>(hbits, w1b, hbuf, sc1, bi1, out);
}

// Round 3
// 87.316 us; speedup vs baseline: 1.3475x; 1.1129x over previous
//
#include <hip/hip_runtime.h>
#include <stdint.h>

#define BB   32
#define CC1  256
#define HH   56
#define WW   56
#define PH   57          // padded (top/left zero row+col)
#define OHH  28
#define OWW  28
#define NPIX (OHH*OWW)   // 784
#define CC2  512
#define EPSV 1e-5f

static __device__ __forceinline__ int popc64(uint64_t v) {
    return __builtin_popcountll(v);
}

// ---------- pack sign(x) into padded layout xbp[b][h+1][w+1][k]  ----------
// Also zeroes the xbp border words and the hbits buffer (first 114816 threads).
__global__ __launch_bounds__(256) void k_binx(const float* __restrict__ x,
                                              uint64_t* __restrict__ xbp,
                                              uint64_t* __restrict__ hbits) {
    int gid = blockIdx.x * 256 + threadIdx.x;         // 401408
    if (gid < 7296) {                                 // top padded row: 32 * 57 * 4
        int b = gid / 228, r = gid % 228;
        xbp[((size_t)(b * PH) * PH + (r >> 2)) * 4 + (r & 3)] = 0ull;
    } else if (gid < 14464) {                         // left padded col rows 1..56: 32 * 56 * 4
        int i = gid - 7296;
        int b = i / 224, r = i % 224;
        xbp[((size_t)(b * PH + (r >> 2) + 1) * PH) * 4 + (r & 3)] = 0ull;
    } else if (gid < 114816) {                        // hbits: 32 * 784 * 4
        hbits[gid - 14464] = 0ull;
    }

    const int NP = BB * HH * WW;
    int pix = gid % NP;
    int cg  = gid / NP;                               // 0..3
    int w = pix % WW;
    int h = (pix / WW) % HH;
    int b = pix / (HH * WW);
    const float* xp = x + ((size_t)(b * CC1 + cg * 64)) * (HH * WW) + h * WW + w;
    uint64_t bits = 0;
    #pragma unroll 8
    for (int c = 0; c < 64; ++c) {
        bits |= (uint64_t)(xp[(size_t)c * (HH * WW)] >= 0.0f) << c;
    }
    xbp[((size_t)((b * PH + h + 1) * PH) + w + 1) * 4 + cg] = bits;
}

// ---------- pack sign(w3) into layout w3t[tap][oc][k] ----------
__global__ __launch_bounds__(256) void k_packw3(const float* __restrict__ w3,
                                                uint64_t* __restrict__ w3t) {
    int id = blockIdx.x * 256 + threadIdx.x;          // 9216
    int k   = id % 4;
    int tap = (id / 4) % 9;
    int oc  = id / 36;
    const float* wp = w3 + (size_t)oc * 2304 + (size_t)(k * 64) * 9 + tap;
    uint64_t bits = 0;
    #pragma unroll 8
    for (int c = 0; c < 64; ++c) {
        bits |= (uint64_t)(wp[c * 9] >= 0.0f) << c;
    }
    w3t[((size_t)tap * CC1 + oc) * 4 + k] = bits;
}

// ---------- pack sign(w1) + fold BN constants + padding corrections ----------
// (runs after k_packw3, so w3t is complete — stream-ordered)
__global__ __launch_bounds__(256) void k_prep2(const float* __restrict__ w1,
                                               uint64_t* __restrict__ w1b,
                                               const uint64_t* __restrict__ w3t,
                                               const float* __restrict__ g3,
                                               const float* __restrict__ b3,
                                               const float* __restrict__ m3,
                                               const float* __restrict__ v3,
                                               const float* __restrict__ g1,
                                               const float* __restrict__ b1,
                                               const float* __restrict__ m1,
                                               const float* __restrict__ v1,
                                               float* __restrict__ sc3,
                                               float* __restrict__ bi3,
                                               float* __restrict__ sc1,
                                               float* __restrict__ bi1,
                                               int* __restrict__ ctop,
                                               int* __restrict__ cleft,
                                               int* __restrict__ ccorn) {
    int id = blockIdx.x * 256 + threadIdx.x;          // 2048
    int k  = id % 4;
    int oc = id / 4;
    const float* wp = w1 + (size_t)oc * 256 + k * 64;
    uint64_t bits = 0;
    #pragma unroll 8
    for (int c = 0; c < 64; ++c) {
        bits |= (uint64_t)(wp[c] >= 0.0f) << c;
    }
    w1b[(size_t)oc * 4 + k] = bits;
    if (k == 0) {
        float s1 = g1[oc] / sqrtf(v1[oc] + EPSV);
        sc1[oc] = s1;
        bi1[oc] = b1[oc] - m1[oc] * s1;
        if (oc < CC1) {
            float s3 = g3[oc] / sqrtf(v3[oc] + EPSV);
            sc3[oc] = s3;
            bi3[oc] = b3[oc] - m3[oc] * s3;
        }
    }
    if (id < CC1) {                                   // padding corrections
        int pt[9];
        #pragma unroll
        for (int t = 0; t < 9; ++t) {
            const uint64_t* p = w3t + ((size_t)t * CC1 + id) * 4;
            pt[t] = popc64(p[0]) + popc64(p[1]) + popc64(p[2]) + popc64(p[3]);
        }
        ctop[id]  = (256 - 2 * pt[0]) + (256 - 2 * pt[1]) + (256 - 2 * pt[2]);
        cleft[id] = (256 - 2 * pt[0]) + (256 - 2 * pt[3]) + (256 - 2 * pt[6]);
        ccorn[id] = (256 - 2 * pt[0]);
    }
}

// ---------- 3x3 stride-2 binary conv + BN + avgpool shortcut + sign-pack ----------
__global__ __launch_bounds__(256, 4) void k_conv3(const float* __restrict__ x,
                                                  const uint64_t* __restrict__ xbp,
                                                  const uint64_t* __restrict__ w3t,
                                                  const float* __restrict__ sc3,
                                                  const float* __restrict__ bi3,
                                                  const int* __restrict__ ctop,
                                                  const int* __restrict__ cleft,
                                                  const int* __restrict__ ccorn,
                                                  float* __restrict__ hbuf,
                                                  uint64_t* __restrict__ hbits) {
    int loc = blockIdx.x * 256 + threadIdx.x;         // 25088
    int ow = loc % OWW;
    int oh = (loc / OWW) % OHH;
    int b  = loc / NPIX;
    int ocg = blockIdx.y;                             // 0..31, 8 oc each

    int tot[8] = {0, 0, 0, 0, 0, 0, 0, 0};
    for (int kh = 0; kh < 3; ++kh) {
        const uint64_t* rp = xbp + ((size_t)((b * PH + 2 * oh + kh) * PH) + 2 * ow) * 4;
        uint64_t t0[4], t1[4], t2[4];
        #pragma unroll
        for (int k = 0; k < 4; ++k) { t0[k] = rp[k]; t1[k] = rp[4 + k]; t2[k] = rp[8 + k]; }
        const uint64_t* wrow = w3t + ((size_t)(kh * 3) * CC1 + ocg * 8) * 4;
        #pragma unroll
        for (int o = 0; o < 8; ++o) {
            const uint64_t* w0  = wrow + (size_t)o * 4;
            const uint64_t* w1p = w0 + (size_t)CC1 * 4;
            const uint64_t* w2p = w0 + (size_t)CC1 * 8;
            int s = tot[o];
            #pragma unroll
            for (int k = 0; k < 4; ++k) s += popc64(t0[k] ^ w0[k]);
            #pragma unroll
            for (int k = 0; k < 4; ++k) s += popc64(t1[k] ^ w1p[k]);
            #pragma unroll
            for (int k = 0; k < 4; ++k) s += popc64(t2[k] ^ w2p[k]);
            tot[o] = s;
        }
    }

    bool top  = (oh == 0);
    bool left = (ow == 0);
    uint64_t hb = 0;
    #pragma unroll
    for (int o = 0; o < 8; ++o) {
        int oc = ocg * 8 + o;
        int corr = (top ? ctop[oc] : 0) + (left ? cleft[oc] : 0)
                 - ((top && left) ? ccorn[oc] : 0);
        float y = (float)(2304 - 2 * tot[o] - corr);
        const float* px = x + ((size_t)(b * CC1 + oc)) * (HH * WW) + (2 * oh) * WW + 2 * ow;
        float2 r0 = *(const float2*)(px);
        float2 r1 = *(const float2*)(px + WW);
        float pool = 0.25f * (r0.x + r0.y + r1.x + r1.y);
        float hv = y * sc3[oc] + bi3[oc] + pool;
        hbuf[((size_t)(b * CC1 + oc)) * NPIX + oh * OWW + ow] = hv;
        hb |= (uint64_t)(hv >= 0.0f) << ((ocg & 7) * 8 + o);
    }
    atomicOr((unsigned long long*)&hbits[(size_t)loc * 4 + (ocg >> 3)],
             (unsigned long long)hb);
}

// ---------- 1x1 binary conv + BN + concat(h,h) shortcut ----------
__global__ __launch_bounds__(256, 4) void k_conv1(const uint64_t* __restrict__ hbits,
                                                  const uint64_t* __restrict__ w1b,
                                                  const float* __restrict__ hbuf,
                                                  const float* __restrict__ sc1,
                                                  const float* __restrict__ bi1,
                                                  float* __restrict__ out) {
    int loc = blockIdx.x * 256 + threadIdx.x;         // 25088
    int p = loc % NPIX;
    int b = loc / NPIX;
    int ocg = blockIdx.y;                             // 0..31, 8 channel-pairs

    uint64_t hw[4];
    const uint64_t* hp = hbits + (size_t)loc * 4;
    #pragma unroll
    for (int k = 0; k < 4; ++k) hw[k] = hp[k];

    #pragma unroll
    for (int o = 0; o < 8; ++o) {
        int oc  = ocg * 8 + o;          // 0..255
        int oc2 = oc + CC1;             // 256..511
        const uint64_t* wa = w1b + (size_t)oc  * 4;
        const uint64_t* wb = w1b + (size_t)oc2 * 4;
        int pa = 0, pb = 0;
        #pragma unroll
        for (int k = 0; k < 4; ++k) pa += popc64(hw[k] ^ wa[k]);
        #pragma unroll
        for (int k = 0; k < 4; ++k) pb += popc64(hw[k] ^ wb[k]);
        float hc = hbuf[((size_t)(b * CC1 + oc)) * NPIX + p];
        float za = (float)(256 - 2 * pa) * sc1[oc]  + bi1[oc]  + hc;
        float zb = (float)(256 - 2 * pb) * sc1[oc2] + bi1[oc2] + hc;
        out[((size_t)(b * CC2 + oc))  * NPIX + p] = za;
        out[((size_t)(b * CC2 + oc2)) * NPIX + p] = zb;
    }
}

extern "C" void kernel_launch(void* const* d_in, const int* in_sizes, int n_in,
                              void* d_out, int out_size, void* d_ws, size_t ws_size,
                              hipStream_t stream) {
    const float* x  = (const float*)d_in[0];
    const float* w3 = (const float*)d_in[1];
    const float* g3 = (const float*)d_in[2];
    const float* b3 = (const float*)d_in[3];
    const float* m3 = (const float*)d_in[4];
    const float* v3 = (const float*)d_in[5];
    const float* w1 = (const float*)d_in[6];
    const float* g1 = (const float*)d_in[7];
    const float* b1 = (const float*)d_in[8];
    const float* m1 = (const float*)d_in[9];
    const float* v1 = (const float*)d_in[10];
    float* out = (float*)d_out;

    uint8_t* ws = (uint8_t*)d_ws;
    size_t off = 0;
    uint64_t* xbp   = (uint64_t*)(ws + off); off += (size_t)BB * PH * PH * 4 * 8;   // 3,326,976
    uint64_t* hbits = (uint64_t*)(ws + off); off += (size_t)BB * NPIX * 4 * 8;      //   802,816
    uint64_t* w3t   = (uint64_t*)(ws + off); off += (size_t)9 * CC1 * 4 * 8;        //    73,728
    uint64_t* w1b   = (uint64_t*)(ws + off); off += (size_t)CC2 * 4 * 8;            //    16,384
    float* sc3 = (float*)(ws + off); off += CC1 * 4;
    float* bi3 = (float*)(ws + off); off += CC1 * 4;
    float* sc1 = (float*)(ws + off); off += CC2 * 4;
    float* bi1 = (float*)(ws + off); off += CC2 * 4;
    int* ctop  = (int*)(ws + off); off += CC1 * 4;
    int* cleft = (int*)(ws + off); off += CC1 * 4;
    int* ccorn = (int*)(ws + off); off += CC1 * 4;
    float* hbuf = (float*)(ws + off);                                               // 25,690,112

    k_binx  <<<dim3(401408 / 256), 256, 0, stream>>>(x, xbp, hbits);
    k_packw3<<<dim3(9216 / 256),   256, 0, stream>>>(w3, w3t);
    k_prep2 <<<dim3(2048 / 256),   256, 0, stream>>>(w1, w1b, w3t, g3, b3, m3, v3,
                                                     g1, b1, m1, v1, sc3, bi3, sc1, bi1,
                                                     ctop, cleft, ccorn);
    k_conv3 <<<dim3(98, 32), 256, 0, stream>>>(x, xbp, w3t, sc3, bi3, ctop, cleft, ccorn,
                                               hbuf, hbits);
    k_conv1 <<<dim3(98, 32), 256, 0, stream>>>(hbits, w1b, hbuf, sc1, bi1, out);
}